// Round 1
// baseline (3446.557 us; speedup 1.0000x reference)
//
#include <hip/hip_runtime.h>
#include <math.h>

#define BS   8
#define NP   4096
#define NC   1024
#define KN   32
#define CIN  128
#define CMID 183
#define COUT 256
#define BN_EPS 1e-5f

// ---- workspace layout (bytes) ----
#define OFF_SQ   0                    // BS*NP floats            = 131072
#define OFF_FPS  131072               // BS*NC ints              = 32768
#define OFF_GRP  163840               // BS*NC*KN ints           = 1048576
#define OFF_A1   1212416              // CMID floats (padded 1K)
#define OFF_B1   1213440
#define OFF_A2   1214464              // COUT floats
#define OFF_B2   1215488
#define OFF_W1P  1216512              // CMID*132 floats = 96624 -> pad 96768
#define OFF_W2P  1313280              // COUT*184 floats = 188416
// total 1501696 bytes

// ============================================================ prep
// sq[i] = (x*x + y*y) + z*z  (exact numpy fp32 order, no fma)
// folded BN params: A = g/sqrt(v+eps), B = (b - m)*A + be
// padded weight copies: W1p [CMID][132] (col 131 = 0), W2p [COUT][184] (col 183 = 0)
__global__ __launch_bounds__(256) void prep_kernel(
    const float* __restrict__ xyz,
    const float* __restrict__ W1, const float* __restrict__ W2,
    const float* __restrict__ b1, const float* __restrict__ g1, const float* __restrict__ be1,
    const float* __restrict__ m1, const float* __restrict__ v1,
    const float* __restrict__ b2, const float* __restrict__ g2, const float* __restrict__ be2,
    const float* __restrict__ m2, const float* __restrict__ v2,
    float* __restrict__ sq, float* __restrict__ A1, float* __restrict__ B1,
    float* __restrict__ A2, float* __restrict__ B2,
    float* __restrict__ W1p, float* __restrict__ W2p) {
  int i = blockIdx.x * 256 + threadIdx.x;
  if (i < BS * NP) {
    #pragma clang fp contract(off)
    float x = xyz[i*3+0], y = xyz[i*3+1], z = xyz[i*3+2];
    sq[i] = (x*x + y*y) + z*z;
  }
  if (i < CMID) { float a = g1[i] / sqrtf(v1[i] + BN_EPS); A1[i] = a; B1[i] = fmaf(b1[i] - m1[i], a, be1[i]); }
  if (i < COUT) { float a = g2[i] / sqrtf(v2[i] + BN_EPS); A2[i] = a; B2[i] = fmaf(b2[i] - m2[i], a, be2[i]); }
  if (i < CMID * 132) { int c = i / 132, k = i % 132; W1p[i] = (k < 131) ? W1[c*131 + k] : 0.f; }
  if (i < COUT * 184) { int c = i / 184, k = i % 184; W2p[i] = (k < 183) ? W2[c*183 + k] : 0.f; }
}

// ============================================================ FPS
// one block per batch; bit-faithful numpy fp32 emulation (no fma, L->R adds),
// argmax tie -> lowest index. Writes fps_idx and center_xyz (exact input copies).
__global__ __launch_bounds__(256) void fps_kernel(
    const float* __restrict__ xyz,
    int* __restrict__ fps_idx, float* __restrict__ center_out) {
  #pragma clang fp contract(off)
  int b = blockIdx.x, t = threadIdx.x;
  const float* p = xyz + (size_t)b * NP * 3;
  __shared__ float s_xyz[NP * 3];          // 48 KB
  __shared__ float s_pval[2][4];
  __shared__ int   s_pidx[2][4];
  for (int i = t; i < NP * 3; i += 256) s_xyz[i] = p[i];
  __syncthreads();
  const int PPT = NP / 256;                // 16 points/thread
  float px[PPT], py[PPT], pz[PPT], dist[PPT];
  int base = t * PPT;
  #pragma unroll
  for (int j = 0; j < PPT; ++j) {
    px[j] = s_xyz[(base+j)*3+0]; py[j] = s_xyz[(base+j)*3+1]; pz[j] = s_xyz[(base+j)*3+2];
    dist[j] = INFINITY;
  }
  int far = 0;
  float cx = s_xyz[0], cy = s_xyz[1], cz = s_xyz[2];
  int lane = t & 63, wave = t >> 6;
  for (int it = 0; it < NC; ++it) {
    if (t == 0) {
      fps_idx[b*NC + it] = far;
      center_out[(size_t)(b*NC + it)*3 + 0] = cx;
      center_out[(size_t)(b*NC + it)*3 + 1] = cy;
      center_out[(size_t)(b*NC + it)*3 + 2] = cz;
    }
    float bv = -1.0f; int bi = 0x7fffffff;
    #pragma unroll
    for (int j = 0; j < PPT; ++j) {
      float dx = px[j] - cx, dy = py[j] - cy, dz = pz[j] - cz;
      float d = (dx*dx + dy*dy) + dz*dz;          // exact order, no fma
      float nd = fminf(dist[j], d);
      dist[j] = nd;
      bool bt = nd > bv;                           // ascending j: tie keeps lowest
      bv = bt ? nd : bv;
      bi = bt ? (base + j) : bi;
    }
    #pragma unroll
    for (int off = 1; off < 64; off <<= 1) {
      float ov = __shfl_xor(bv, off);
      int   oi = __shfl_xor(bi, off);
      bool take = (ov > bv) || (ov == bv && oi < bi);
      bv = take ? ov : bv; bi = take ? oi : bi;
    }
    int par = it & 1;
    if (lane == 0) { s_pval[par][wave] = bv; s_pidx[par][wave] = bi; }
    __syncthreads();
    bv = s_pval[par][0]; bi = s_pidx[par][0];
    #pragma unroll
    for (int w = 1; w < 4; ++w) {
      float ov = s_pval[par][w]; int oi = s_pidx[par][w];
      bool take = (ov > bv) || (ov == bv && oi < bi);
      bv = take ? ov : bv; bi = take ? oi : bi;
    }
    far = bi;
    cx = s_xyz[far*3+0]; cy = s_xyz[far*3+1]; cz = s_xyz[far*3+2];
  }
}

// ============================================================ kNN (selected centers only)
// d_ij = (sq_i - 2*dot) + sq_j exactly as reference; 32x min-extraction,
// tie -> lowest index (matches lax.top_k membership). Order irrelevant downstream.
__global__ __launch_bounds__(256) void knn_kernel(
    const float* __restrict__ xyz, const float* __restrict__ sq,
    const int* __restrict__ fps_idx, int* __restrict__ grp) {
  #pragma clang fp contract(off)
  int L = blockIdx.x;
  int b = L & 7, ci = L >> 3;
  int t = threadIdx.x;
  const float* p   = xyz + (size_t)b * NP * 3;
  const float* sqb = sq + b * NP;
  __shared__ float s_d[NP];                // 16 KB
  __shared__ float s_pval[2][4];
  __shared__ int   s_pidx[2][4];
  int center = fps_idx[b*NC + ci];
  float cx = p[center*3+0], cy = p[center*3+1], cz = p[center*3+2];
  float sqi = sqb[center];
  const int PPT = NP / 256;                // 16
  #pragma unroll
  for (int k = 0; k < PPT; ++k) {
    int j = t + k * 256;
    float dot = (cx*p[j*3+0] + cy*p[j*3+1]) + cz*p[j*3+2];   // L->R, no fma
    s_d[j] = (sqi - 2.0f*dot) + sqb[j];
  }
  __syncthreads();
  // per-thread cached local min over its private chunk [t*16, t*16+16)
  int base = t * PPT;
  float lv = INFINITY; int li = 0x7fffffff;
  #pragma unroll
  for (int j = 0; j < PPT; ++j) {
    float v = s_d[base + j];
    bool bt = v < lv;
    lv = bt ? v : lv; li = bt ? (base + j) : li;
  }
  int lane = t & 63, wave = t >> 6;
  int myidx = 0;
  for (int it = 0; it < KN; ++it) {
    float bv = lv; int bi = li;
    #pragma unroll
    for (int off = 1; off < 64; off <<= 1) {
      float ov = __shfl_xor(bv, off);
      int   oi = __shfl_xor(bi, off);
      bool take = (ov < bv) || (ov == bv && oi < bi);
      bv = take ? ov : bv; bi = take ? oi : bi;
    }
    int par = it & 1;
    if (lane == 0) { s_pval[par][wave] = bv; s_pidx[par][wave] = bi; }
    __syncthreads();
    bv = s_pval[par][0]; bi = s_pidx[par][0];
    #pragma unroll
    for (int w = 1; w < 4; ++w) {
      float ov = s_pval[par][w]; int oi = s_pidx[par][w];
      bool take = (ov < bv) || (ov == bv && oi < bi);
      bv = take ? ov : bv; bi = take ? oi : bi;
    }
    if (t == it) myidx = bi;               // thread `it` records winner
    if ((bi >> 4) == t) {                  // owner invalidates + rescans its chunk
      s_d[bi] = INFINITY;
      lv = INFINITY; li = 0x7fffffff;
      #pragma unroll
      for (int j = 0; j < PPT; ++j) {
        float v = s_d[base + j];
        bool bt = v < lv;
        lv = bt ? v : lv; li = bt ? (base + j) : li;
      }
    }
  }
  if (t < KN) grp[((size_t)(b*NC + ci))*KN + t] = myidx;
}

// ============================================================ fused MLP + maxpool
// one block per center: gather 32x131 tile -> LDS, two fp32 layers, max over k.
__global__ __launch_bounds__(256) void mlp_kernel(
    const float* __restrict__ xyz, const float* __restrict__ fea,
    const float* __restrict__ W1p, const float* __restrict__ W2p,
    const float* __restrict__ A1, const float* __restrict__ B1,
    const float* __restrict__ A2, const float* __restrict__ B2,
    const int* __restrict__ grp, const float* __restrict__ center_xyz,
    float* __restrict__ new_fea) {
  int L = blockIdx.x;
  int b = L & 7, ci = L >> 3;              // batch-per-XCD swizzle (L2 locality)
  int t = threadIdx.x;
  __shared__ float s_x[32][133];           // cols 0..127 fea, 128..130 rel, 131 zero
  __shared__ float s_y1[184][32];          // transposed; row 183 zeroed
  __shared__ float s_y2[256][33];
  __shared__ int   s_gidx[32];
  __shared__ float s_c[3];
  size_t gbase = (size_t)(b*NC + ci);
  if (t < 32) s_gidx[t] = grp[gbase*KN + t];
  if (t < 3)  s_c[t] = center_xyz[gbase*3 + t];
  if (t < 32) { s_x[t][131] = 0.f; s_x[t][132] = 0.f; s_y1[183][t] = 0.f; }
  __syncthreads();
  { // stage features: 8 threads/row, 16 floats each
    int r = t >> 3, q0 = (t & 7) * 16;
    const float* src = fea + ((size_t)b*NP + s_gidx[r])*CIN + q0;
    #pragma unroll
    for (int q = 0; q < 16; q += 4) {
      float4 v = *(const float4*)(src + q);
      s_x[r][q0+q+0] = v.x; s_x[r][q0+q+1] = v.y; s_x[r][q0+q+2] = v.z; s_x[r][q0+q+3] = v.w;
    }
  }
  if (t < 32) {
    const float* g = xyz + ((size_t)b*NP + s_gidx[t])*3;
    s_x[t][128] = g[0] - s_c[0]; s_x[t][129] = g[1] - s_c[1]; s_x[t][130] = g[2] - s_c[2];
  }
  __syncthreads();
  int lane = t & 63, wave = t >> 6;
  int row = lane & 31;
  int hw = wave*2 + (lane >> 5);           // 0..7 half-wave id
  // ---- layer 1: chans [hw*23, hw*23+23) (last gets 22)
  {
    int c0 = hw * 23;
    float acc[23];
    #pragma unroll
    for (int m = 0; m < 23; ++m) acc[m] = 0.f;
    for (int k0 = 0; k0 < 128; k0 += 8) {
      float xc[8];
      #pragma unroll
      for (int kk = 0; kk < 8; ++kk) xc[kk] = s_x[row][k0+kk];
      #pragma unroll
      for (int m = 0; m < 23; ++m) {
        int c = c0 + m;
        if (c < CMID) {
          const float* wr = W1p + c*132 + k0;
          float4 wa = *(const float4*)wr;
          float4 wb = *(const float4*)(wr + 4);
          acc[m] = fmaf(xc[0],wa.x,acc[m]); acc[m] = fmaf(xc[1],wa.y,acc[m]);
          acc[m] = fmaf(xc[2],wa.z,acc[m]); acc[m] = fmaf(xc[3],wa.w,acc[m]);
          acc[m] = fmaf(xc[4],wb.x,acc[m]); acc[m] = fmaf(xc[5],wb.y,acc[m]);
          acc[m] = fmaf(xc[6],wb.z,acc[m]); acc[m] = fmaf(xc[7],wb.w,acc[m]);
        }
      }
    }
    { // tail k = 128..131 (col 131 is zero on both sides)
      float xc[4];
      #pragma unroll
      for (int kk = 0; kk < 4; ++kk) xc[kk] = s_x[row][128+kk];
      #pragma unroll
      for (int m = 0; m < 23; ++m) {
        int c = c0 + m;
        if (c < CMID) {
          float4 wa = *(const float4*)(W1p + c*132 + 128);
          acc[m] = fmaf(xc[0],wa.x,acc[m]); acc[m] = fmaf(xc[1],wa.y,acc[m]);
          acc[m] = fmaf(xc[2],wa.z,acc[m]); acc[m] = fmaf(xc[3],wa.w,acc[m]);
        }
      }
    }
    #pragma unroll
    for (int m = 0; m < 23; ++m) {
      int c = c0 + m;
      if (c < CMID) s_y1[c][row] = fmaxf(fmaf(acc[m], A1[c], B1[c]), 0.f);
    }
  }
  __syncthreads();
  // ---- layer 2: chans [hw*32, hw*32+32)
  {
    int c0 = hw * 32;
    float acc[32];
    #pragma unroll
    for (int m = 0; m < 32; ++m) acc[m] = 0.f;
    for (int k0 = 0; k0 < 176; k0 += 8) {
      float yc[8];
      #pragma unroll
      for (int kk = 0; kk < 8; ++kk) yc[kk] = s_y1[k0+kk][row];
      #pragma unroll
      for (int m = 0; m < 32; ++m) {
        const float* wr = W2p + (c0+m)*184 + k0;
        float4 wa = *(const float4*)wr;
        float4 wb = *(const float4*)(wr + 4);
        acc[m] = fmaf(yc[0],wa.x,acc[m]); acc[m] = fmaf(yc[1],wa.y,acc[m]);
        acc[m] = fmaf(yc[2],wa.z,acc[m]); acc[m] = fmaf(yc[3],wa.w,acc[m]);
        acc[m] = fmaf(yc[4],wb.x,acc[m]); acc[m] = fmaf(yc[5],wb.y,acc[m]);
        acc[m] = fmaf(yc[6],wb.z,acc[m]); acc[m] = fmaf(yc[7],wb.w,acc[m]);
      }
    }
    #pragma unroll
    for (int tl = 0; tl < 2; ++tl) {       // tails 176..179, 180..183 (183 zero)
      int k0 = 176 + tl*4;
      float yc[4];
      #pragma unroll
      for (int kk = 0; kk < 4; ++kk) yc[kk] = s_y1[k0+kk][row];
      #pragma unroll
      for (int m = 0; m < 32; ++m) {
        float4 wa = *(const float4*)(W2p + (c0+m)*184 + k0);
        acc[m] = fmaf(yc[0],wa.x,acc[m]); acc[m] = fmaf(yc[1],wa.y,acc[m]);
        acc[m] = fmaf(yc[2],wa.z,acc[m]); acc[m] = fmaf(yc[3],wa.w,acc[m]);
      }
    }
    #pragma unroll
    for (int m = 0; m < 32; ++m) {
      int c = c0 + m;
      s_y2[c][row] = fmaxf(fmaf(acc[m], A2[c], B2[c]), 0.f);
    }
  }
  __syncthreads();
  // ---- max over the 32 neighbors; thread t == channel
  {
    float mv = s_y2[t][0];
    #pragma unroll
    for (int r = 1; r < 32; ++r) mv = fmaxf(mv, s_y2[t][r]);
    new_fea[gbase*COUT + t] = mv;
  }
}

// ============================================================ launch
extern "C" void kernel_launch(void* const* d_in, const int* in_sizes, int n_in,
                              void* d_out, int out_size, void* d_ws, size_t ws_size,
                              hipStream_t stream) {
  const float* xyz = (const float*)d_in[0];
  const float* fea = (const float*)d_in[1];
  const float* W1  = (const float*)d_in[2];
  const float* b1  = (const float*)d_in[3];
  const float* g1  = (const float*)d_in[4];
  const float* be1 = (const float*)d_in[5];
  const float* m1  = (const float*)d_in[6];
  const float* v1  = (const float*)d_in[7];
  const float* W2  = (const float*)d_in[8];
  const float* b2  = (const float*)d_in[9];
  const float* g2  = (const float*)d_in[10];
  const float* be2 = (const float*)d_in[11];
  const float* m2  = (const float*)d_in[12];
  const float* v2  = (const float*)d_in[13];

  char* ws = (char*)d_ws;
  float* sq      = (float*)(ws + OFF_SQ);
  int*   fpsi    = (int*)  (ws + OFF_FPS);
  int*   grp     = (int*)  (ws + OFF_GRP);
  float* A1      = (float*)(ws + OFF_A1);
  float* B1      = (float*)(ws + OFF_B1);
  float* A2      = (float*)(ws + OFF_A2);
  float* B2      = (float*)(ws + OFF_B2);
  float* W1p     = (float*)(ws + OFF_W1P);
  float* W2p     = (float*)(ws + OFF_W2P);

  float* out        = (float*)d_out;
  float* center_out = out;                   // [BS][NC][3]
  float* new_fea    = out + (size_t)BS*NC*3; // [BS][NC][COUT]

  prep_kernel<<<184, 256, 0, stream>>>(xyz, W1, W2, b1,g1,be1,m1,v1, b2,g2,be2,m2,v2,
                                       sq, A1,B1,A2,B2, W1p, W2p);
  fps_kernel<<<BS, 256, 0, stream>>>(xyz, fpsi, center_out);
  knn_kernel<<<BS*NC, 256, 0, stream>>>(xyz, sq, fpsi, grp);
  mlp_kernel<<<BS*NC, 256, 0, stream>>>(xyz, fea, W1p, W2p, A1,B1,A2,B2,
                                        grp, center_out, new_fea);
}

// Round 2
// 1299.581 us; speedup vs baseline: 2.6521x; 2.6521x over previous
//
#include <hip/hip_runtime.h>
#include <hip/hip_bf16.h>
#include <math.h>

#define BS   8
#define NP   4096
#define NC   1024
#define KN   32
#define CIN  128
#define CMID 183
#define COUT 256
#define BN_EPS 1e-5f

// ---- workspace layout (bytes) ----
#define OFF_SQ   0                    // BS*NP floats            = 131072
#define OFF_FPS  131072               // BS*NC ints              = 32768
#define OFF_GRP  163840               // BS*NC*KN ints           = 1048576 -> ends 1212416
#define OFF_A1   1212416              // 192 floats (pad 1K)
#define OFF_B1   1213440
#define OFF_A2   1214464              // 256 floats
#define OFF_B2   1215488
#define OFF_W1F  1216512              // 30720 u16 = 61440 B  (B-frag packed, 192x160)
#define OFF_W2F  1277952              // 49152 u16 = 98304 B  (B-frag packed, 256x192)
// total 1376256 bytes

typedef float  f32x4 __attribute__((ext_vector_type(4)));
typedef short  s16x8 __attribute__((ext_vector_type(8)));
typedef unsigned short u16;
typedef u16    u16x8 __attribute__((ext_vector_type(8)));

static __device__ __forceinline__ u16 f2bf(float f) {
  __hip_bfloat16 h = __float2bfloat16(f);   // RNE
  return __builtin_bit_cast(u16, h);
}

// ============================================================ prep
// sq[i]=(x*x+y*y)+z*z exact numpy order; folded BN (A,B), zero-padded;
// weights packed to bf16 MFMA B-fragment order:
//   idx = ((nt*KT + kt)*64 + lane)*8 + j ; value = W[n= nt*16+(lane&15)][k= kt*32+(lane>>4)*8+j]
__global__ __launch_bounds__(256) void prep_kernel(
    const float* __restrict__ xyz,
    const float* __restrict__ W1, const float* __restrict__ W2,
    const float* __restrict__ b1, const float* __restrict__ g1, const float* __restrict__ be1,
    const float* __restrict__ m1, const float* __restrict__ v1,
    const float* __restrict__ b2, const float* __restrict__ g2, const float* __restrict__ be2,
    const float* __restrict__ m2, const float* __restrict__ v2,
    float* __restrict__ sq, float* __restrict__ A1, float* __restrict__ B1,
    float* __restrict__ A2, float* __restrict__ B2,
    u16* __restrict__ W1f, u16* __restrict__ W2f) {
  int i = blockIdx.x * 256 + threadIdx.x;
  if (i < BS * NP) {
    #pragma clang fp contract(off)
    float x = xyz[i*3+0], y = xyz[i*3+1], z = xyz[i*3+2];
    sq[i] = (x*x + y*y) + z*z;
  }
  if (i < 192) {
    float a = 0.f, bb = 0.f;
    if (i < CMID) { a = g1[i] / sqrtf(v1[i] + BN_EPS); bb = fmaf(b1[i] - m1[i], a, be1[i]); }
    A1[i] = a; B1[i] = bb;
  }
  if (i < COUT) { float a = g2[i] / sqrtf(v2[i] + BN_EPS); A2[i] = a; B2[i] = fmaf(b2[i] - m2[i], a, be2[i]); }
  if (i < 30720) {               // W1f: 12 N-tiles x 5 K-tiles
    int j = i & 7, lane = (i >> 3) & 63, r = i >> 9;
    int kt = r % 5, nt = r / 5;
    int n = nt*16 + (lane & 15);
    int k = kt*32 + ((lane >> 4) << 3) + j;
    W1f[i] = (n < CMID && k < 131) ? f2bf(W1[n*131 + k]) : (u16)0;
  }
  if (i < 49152) {               // W2f: 16 N-tiles x 6 K-tiles
    int j = i & 7, lane = (i >> 3) & 63, r = i >> 9;
    int kt = r % 6, nt = r / 6;
    int n = nt*16 + (lane & 15);
    int k = kt*32 + ((lane >> 4) << 3) + j;
    W2f[i] = (k < CMID) ? f2bf(W2[n*CMID + k]) : (u16)0;
  }
}

// ============================================================ FPS (unchanged, bit-faithful)
__global__ __launch_bounds__(256) void fps_kernel(
    const float* __restrict__ xyz,
    int* __restrict__ fps_idx, float* __restrict__ center_out) {
  #pragma clang fp contract(off)
  int b = blockIdx.x, t = threadIdx.x;
  const float* p = xyz + (size_t)b * NP * 3;
  __shared__ float s_xyz[NP * 3];
  __shared__ float s_pval[2][4];
  __shared__ int   s_pidx[2][4];
  for (int i = t; i < NP * 3; i += 256) s_xyz[i] = p[i];
  __syncthreads();
  const int PPT = NP / 256;
  float px[PPT], py[PPT], pz[PPT], dist[PPT];
  int base = t * PPT;
  #pragma unroll
  for (int j = 0; j < PPT; ++j) {
    px[j] = s_xyz[(base+j)*3+0]; py[j] = s_xyz[(base+j)*3+1]; pz[j] = s_xyz[(base+j)*3+2];
    dist[j] = INFINITY;
  }
  int far = 0;
  float cx = s_xyz[0], cy = s_xyz[1], cz = s_xyz[2];
  int lane = t & 63, wave = t >> 6;
  for (int it = 0; it < NC; ++it) {
    if (t == 0) {
      fps_idx[b*NC + it] = far;
      center_out[(size_t)(b*NC + it)*3 + 0] = cx;
      center_out[(size_t)(b*NC + it)*3 + 1] = cy;
      center_out[(size_t)(b*NC + it)*3 + 2] = cz;
    }
    float bv = -1.0f; int bi = 0x7fffffff;
    #pragma unroll
    for (int j = 0; j < PPT; ++j) {
      float dx = px[j] - cx, dy = py[j] - cy, dz = pz[j] - cz;
      float d = (dx*dx + dy*dy) + dz*dz;
      float nd = fminf(dist[j], d);
      dist[j] = nd;
      bool bt = nd > bv;
      bv = bt ? nd : bv;
      bi = bt ? (base + j) : bi;
    }
    #pragma unroll
    for (int off = 1; off < 64; off <<= 1) {
      float ov = __shfl_xor(bv, off);
      int   oi = __shfl_xor(bi, off);
      bool take = (ov > bv) || (ov == bv && oi < bi);
      bv = take ? ov : bv; bi = take ? oi : bi;
    }
    int par = it & 1;
    if (lane == 0) { s_pval[par][wave] = bv; s_pidx[par][wave] = bi; }
    __syncthreads();
    bv = s_pval[par][0]; bi = s_pidx[par][0];
    #pragma unroll
    for (int w = 1; w < 4; ++w) {
      float ov = s_pval[par][w]; int oi = s_pidx[par][w];
      bool take = (ov > bv) || (ov == bv && oi < bi);
      bv = take ? ov : bv; bi = take ? oi : bi;
    }
    far = bi;
    cx = s_xyz[far*3+0]; cy = s_xyz[far*3+1]; cz = s_xyz[far*3+2];
  }
}

// ============================================================ kNN (unchanged)
__global__ __launch_bounds__(256) void knn_kernel(
    const float* __restrict__ xyz, const float* __restrict__ sq,
    const int* __restrict__ fps_idx, int* __restrict__ grp) {
  #pragma clang fp contract(off)
  int L = blockIdx.x;
  int b = L & 7, ci = L >> 3;
  int t = threadIdx.x;
  const float* p   = xyz + (size_t)b * NP * 3;
  const float* sqb = sq + b * NP;
  __shared__ float s_d[NP];
  __shared__ float s_pval[2][4];
  __shared__ int   s_pidx[2][4];
  int center = fps_idx[b*NC + ci];
  float cx = p[center*3+0], cy = p[center*3+1], cz = p[center*3+2];
  float sqi = sqb[center];
  const int PPT = NP / 256;
  #pragma unroll
  for (int k = 0; k < PPT; ++k) {
    int j = t + k * 256;
    float dot = (cx*p[j*3+0] + cy*p[j*3+1]) + cz*p[j*3+2];
    s_d[j] = (sqi - 2.0f*dot) + sqb[j];
  }
  __syncthreads();
  int base = t * PPT;
  float lv = INFINITY; int li = 0x7fffffff;
  #pragma unroll
  for (int j = 0; j < PPT; ++j) {
    float v = s_d[base + j];
    bool bt = v < lv;
    lv = bt ? v : lv; li = bt ? (base + j) : li;
  }
  int lane = t & 63, wave = t >> 6;
  int myidx = 0;
  for (int it = 0; it < KN; ++it) {
    float bv = lv; int bi = li;
    #pragma unroll
    for (int off = 1; off < 64; off <<= 1) {
      float ov = __shfl_xor(bv, off);
      int   oi = __shfl_xor(bi, off);
      bool take = (ov < bv) || (ov == bv && oi < bi);
      bv = take ? ov : bv; bi = take ? oi : bi;
    }
    int par = it & 1;
    if (lane == 0) { s_pval[par][wave] = bv; s_pidx[par][wave] = bi; }
    __syncthreads();
    bv = s_pval[par][0]; bi = s_pidx[par][0];
    #pragma unroll
    for (int w = 1; w < 4; ++w) {
      float ov = s_pval[par][w]; int oi = s_pidx[par][w];
      bool take = (ov < bv) || (ov == bv && oi < bi);
      bv = take ? ov : bv; bi = take ? oi : bi;
    }
    if (t == it) myidx = bi;
    if ((bi >> 4) == t) {
      s_d[bi] = INFINITY;
      lv = INFINITY; li = 0x7fffffff;
      #pragma unroll
      for (int j = 0; j < PPT; ++j) {
        float v = s_d[base + j];
        bool bt = v < lv;
        lv = bt ? v : lv; li = bt ? (base + j) : li;
      }
    }
  }
  if (t < KN) grp[((size_t)(b*NC + ci))*KN + t] = myidx;
}

// ============================================================ fused MLP + maxpool (MFMA bf16)
// 2 centers per block (M=64 rows). L1: K 131->160 (5 Ktiles), N 183->192 (12 Ntiles).
// L2: K 183->192 (6 Ktiles), N=256 (16 Ntiles). Wave w owns Ntile quarter.
// A-frag: row=lane&15, k=(lane>>4)*8+j (ds_read_b128 from LDS).
// B-frag: pre-packed in global (coalesced 16B/lane, L2-resident).
// C-frag: col=lane&15, row=(lane>>4)*4+reg (m89-verified).
__global__ __launch_bounds__(256) void mlp_kernel(
    const float* __restrict__ xyz, const float* __restrict__ fea,
    const u16* __restrict__ W1f, const u16* __restrict__ W2f,
    const float* __restrict__ A1, const float* __restrict__ B1,
    const float* __restrict__ A2, const float* __restrict__ B2,
    const int* __restrict__ grp, const float* __restrict__ center_xyz,
    float* __restrict__ new_fea) {
  int L = blockIdx.x;
  int b = L & 7, pi = L >> 3;              // batch-per-XCD swizzle; pi = center-pair
  size_t gbase = (size_t)b * NC + pi * 2;  // first of 2 centers
  int t = threadIdx.x;
  int lane = t & 63, w = t >> 6;

  __shared__ u16 sx[64][168];              // 64 rows x 160 bf16 K (stride 168: 84dw%32=20 -> <=2-way)
  __shared__ u16 sy1[64][200];             // 64 rows x 192 bf16 K (stride 200: 100dw%32=4 -> 2-way)
  __shared__ int s_gidx[64];
  __shared__ float s_c[2][3];

  if (t < 64) s_gidx[t] = grp[(gbase + (t >> 5)) * KN + (t & 31)];
  if (t < 6)  s_c[t/3][t%3] = center_xyz[(gbase + t/3)*3 + (t%3)];
  __syncthreads();

  { // stage features: thread t -> row t>>2, 32 floats at (t&3)*32; fp32->bf16 RNE
    int r = t >> 2, q0 = (t & 3) * 32;
    const float* src = fea + ((size_t)b*NP + s_gidx[r])*CIN + q0;
    #pragma unroll
    for (int j = 0; j < 32; j += 8) {
      float4 v0 = *(const float4*)(src + j);
      float4 v1 = *(const float4*)(src + j + 4);
      u16x8 pk;
      pk[0]=f2bf(v0.x); pk[1]=f2bf(v0.y); pk[2]=f2bf(v0.z); pk[3]=f2bf(v0.w);
      pk[4]=f2bf(v1.x); pk[5]=f2bf(v1.y); pk[6]=f2bf(v1.z); pk[7]=f2bf(v1.w);
      *(u16x8*)&sx[r][q0 + j] = pk;
    }
  }
  if (t < 64) { // rel coords + K-pad zeros
    int c = t >> 5;
    const float* g = xyz + ((size_t)b*NP + s_gidx[t])*3;
    sx[t][128] = f2bf(g[0] - s_c[c][0]);
    sx[t][129] = f2bf(g[1] - s_c[c][1]);
    sx[t][130] = f2bf(g[2] - s_c[c][2]);
    #pragma unroll
    for (int j = 131; j < 160; ++j) sx[t][j] = 0;
  }
  __syncthreads();

  const f32x4 zero = {0.f, 0.f, 0.f, 0.f};

  // ---- layer 1: wave w computes N-tiles w*3..w*3+2 over all 4 M-tiles
  {
    f32x4 acc[4][3];
    #pragma unroll
    for (int mt = 0; mt < 4; ++mt)
      #pragma unroll
      for (int nt = 0; nt < 3; ++nt) acc[mt][nt] = zero;
    #pragma unroll
    for (int kt = 0; kt < 5; ++kt) {
      s16x8 a[4];
      #pragma unroll
      for (int mt = 0; mt < 4; ++mt)
        a[mt] = *(const s16x8*)&sx[mt*16 + (lane & 15)][kt*32 + ((lane >> 4) << 3)];
      s16x8 bf[3];
      #pragma unroll
      for (int nt = 0; nt < 3; ++nt)
        bf[nt] = *(const s16x8*)&W1f[(((w*3 + nt)*5 + kt)*64 + lane) * 8];
      #pragma unroll
      for (int mt = 0; mt < 4; ++mt)
        #pragma unroll
        for (int nt = 0; nt < 3; ++nt)
          acc[mt][nt] = __builtin_amdgcn_mfma_f32_16x16x32_bf16(a[mt], bf[nt], acc[mt][nt], 0, 0, 0);
    }
    #pragma unroll
    for (int nt = 0; nt < 3; ++nt) {
      int c = w*48 + nt*16 + (lane & 15);
      float av = A1[c], bv = B1[c];
      #pragma unroll
      for (int mt = 0; mt < 4; ++mt) {
        #pragma unroll
        for (int r = 0; r < 4; ++r) {
          float v = fmaxf(fmaf(acc[mt][nt][r], av, bv), 0.f);
          sy1[mt*16 + ((lane >> 4) << 2) + r][c] = f2bf(v);
        }
      }
    }
  }
  __syncthreads();

  // ---- layer 2 + BN/ReLU + maxpool over 32 neighbors
  {
    f32x4 acc[4][4];
    #pragma unroll
    for (int mt = 0; mt < 4; ++mt)
      #pragma unroll
      for (int nt = 0; nt < 4; ++nt) acc[mt][nt] = zero;
    #pragma unroll
    for (int kt = 0; kt < 6; ++kt) {
      s16x8 a[4];
      #pragma unroll
      for (int mt = 0; mt < 4; ++mt)
        a[mt] = *(const s16x8*)&sy1[mt*16 + (lane & 15)][kt*32 + ((lane >> 4) << 3)];
      s16x8 bf[4];
      #pragma unroll
      for (int nt = 0; nt < 4; ++nt)
        bf[nt] = *(const s16x8*)&W2f[(((w*4 + nt)*6 + kt)*64 + lane) * 8];
      #pragma unroll
      for (int mt = 0; mt < 4; ++mt)
        #pragma unroll
        for (int nt = 0; nt < 4; ++nt)
          acc[mt][nt] = __builtin_amdgcn_mfma_f32_16x16x32_bf16(a[mt], bf[nt], acc[mt][nt], 0, 0, 0);
    }
    #pragma unroll
    for (int nt = 0; nt < 4; ++nt) {
      int c = w*64 + nt*16 + (lane & 15);
      float av = A2[c], bv = B2[c];
      float c0 = 0.f, c1 = 0.f;   // relu => all vals >= 0, so 0 is identity for max
      #pragma unroll
      for (int mt = 0; mt < 2; ++mt)
        #pragma unroll
        for (int r = 0; r < 4; ++r)
          c0 = fmaxf(c0, fmaf(acc[mt][nt][r], av, bv));
      #pragma unroll
      for (int mt = 2; mt < 4; ++mt)
        #pragma unroll
        for (int r = 0; r < 4; ++r)
          c1 = fmaxf(c1, fmaf(acc[mt][nt][r], av, bv));
      // reduce across the 4 row-groups (lanes sharing lane&15)
      c0 = fmaxf(c0, __shfl_xor(c0, 16)); c0 = fmaxf(c0, __shfl_xor(c0, 32));
      c1 = fmaxf(c1, __shfl_xor(c1, 16)); c1 = fmaxf(c1, __shfl_xor(c1, 32));
      if (lane < 16)      new_fea[gbase*COUT + c] = c0;
      else if (lane < 32) new_fea[(gbase + 1)*COUT + c] = c1;
    }
  }
}

// ============================================================ launch
extern "C" void kernel_launch(void* const* d_in, const int* in_sizes, int n_in,
                              void* d_out, int out_size, void* d_ws, size_t ws_size,
                              hipStream_t stream) {
  const float* xyz = (const float*)d_in[0];
  const float* fea = (const float*)d_in[1];
  const float* W1  = (const float*)d_in[2];
  const float* b1  = (const float*)d_in[3];
  const float* g1  = (const float*)d_in[4];
  const float* be1 = (const float*)d_in[5];
  const float* m1  = (const float*)d_in[6];
  const float* v1  = (const float*)d_in[7];
  const float* W2  = (const float*)d_in[8];
  const float* b2  = (const float*)d_in[9];
  const float* g2  = (const float*)d_in[10];
  const float* be2 = (const float*)d_in[11];
  const float* m2  = (const float*)d_in[12];
  const float* v2  = (const float*)d_in[13];

  char* ws = (char*)d_ws;
  float* sq   = (float*)(ws + OFF_SQ);
  int*   fpsi = (int*)  (ws + OFF_FPS);
  int*   grp  = (int*)  (ws + OFF_GRP);
  float* A1   = (float*)(ws + OFF_A1);
  float* B1   = (float*)(ws + OFF_B1);
  float* A2   = (float*)(ws + OFF_A2);
  float* B2   = (float*)(ws + OFF_B2);
  u16*   W1f  = (u16*)  (ws + OFF_W1F);
  u16*   W2f  = (u16*)  (ws + OFF_W2F);

  float* out        = (float*)d_out;
  float* center_out = out;                   // [BS][NC][3]
  float* new_fea    = out + (size_t)BS*NC*3; // [BS][NC][COUT]

  prep_kernel<<<192, 256, 0, stream>>>(xyz, W1, W2, b1,g1,be1,m1,v1, b2,g2,be2,m2,v2,
                                       sq, A1,B1,A2,B2, W1f, W2f);
  fps_kernel<<<BS, 256, 0, stream>>>(xyz, fpsi, center_out);
  knn_kernel<<<BS*NC, 256, 0, stream>>>(xyz, sq, fpsi, grp);
  mlp_kernel<<<BS*NC/2, 256, 0, stream>>>(xyz, fea, W1f, W2f, A1,B1,A2,B2,
                                          grp, center_out, new_fea);
}

// Round 4
// 1042.411 us; speedup vs baseline: 3.3063x; 1.2467x over previous
//
#include <hip/hip_runtime.h>
#include <hip/hip_bf16.h>
#include <math.h>

#define BS   8
#define NP   4096
#define NC   1024
#define KN   32
#define CIN  128
#define CMID 183
#define COUT 256
#define BN_EPS 1e-5f

// ---- workspace layout (bytes) ----
#define OFF_SQ   0                    // BS*NP floats            = 131072
#define OFF_FPS  131072               // BS*NC ints              = 32768
#define OFF_GRP  163840               // BS*NC*KN ints           = 1048576 -> ends 1212416
#define OFF_A1   1212416              // 192 floats (pad 1K)
#define OFF_B1   1213440
#define OFF_A2   1214464              // 256 floats
#define OFF_B2   1215488
#define OFF_W1F  1216512              // 30720 u16 = 61440 B  (B-frag packed, 192x160)
#define OFF_W2F  1277952              // 49152 u16 = 98304 B  (B-frag packed, 256x192)
// total 1376256 bytes

typedef float  f32x4 __attribute__((ext_vector_type(4)));
typedef short  s16x8 __attribute__((ext_vector_type(8)));
typedef unsigned short u16;
typedef u16    u16x8 __attribute__((ext_vector_type(8)));
typedef unsigned long long u64;
typedef unsigned int u32;

static __device__ __forceinline__ u16 f2bf(float f) {
  __hip_bfloat16 h = __float2bfloat16(f);   // RNE
  return __builtin_bit_cast(u16, h);
}

// ============================================================ prep
__global__ __launch_bounds__(256) void prep_kernel(
    const float* __restrict__ xyz,
    const float* __restrict__ W1, const float* __restrict__ W2,
    const float* __restrict__ b1, const float* __restrict__ g1, const float* __restrict__ be1,
    const float* __restrict__ m1, const float* __restrict__ v1,
    const float* __restrict__ b2, const float* __restrict__ g2, const float* __restrict__ be2,
    const float* __restrict__ m2, const float* __restrict__ v2,
    float* __restrict__ sq, float* __restrict__ A1, float* __restrict__ B1,
    float* __restrict__ A2, float* __restrict__ B2,
    u16* __restrict__ W1f, u16* __restrict__ W2f) {
  int i = blockIdx.x * 256 + threadIdx.x;
  if (i < BS * NP) {
    #pragma clang fp contract(off)
    float x = xyz[i*3+0], y = xyz[i*3+1], z = xyz[i*3+2];
    sq[i] = (x*x + y*y) + z*z;
  }
  if (i < 192) {
    float a = 0.f, bb = 0.f;
    if (i < CMID) { a = g1[i] / sqrtf(v1[i] + BN_EPS); bb = fmaf(b1[i] - m1[i], a, be1[i]); }
    A1[i] = a; B1[i] = bb;
  }
  if (i < COUT) { float a = g2[i] / sqrtf(v2[i] + BN_EPS); A2[i] = a; B2[i] = fmaf(b2[i] - m2[i], a, be2[i]); }
  if (i < 30720) {               // W1f: 12 N-tiles x 5 K-tiles
    int j = i & 7, lane = (i >> 3) & 63, r = i >> 9;
    int kt = r % 5, nt = r / 5;
    int n = nt*16 + (lane & 15);
    int k = kt*32 + ((lane >> 4) << 3) + j;
    W1f[i] = (n < CMID && k < 131) ? f2bf(W1[n*131 + k]) : (u16)0;
  }
  if (i < 49152) {               // W2f: 16 N-tiles x 6 K-tiles
    int j = i & 7, lane = (i >> 3) & 63, r = i >> 9;
    int kt = r % 6, nt = r / 6;
    int n = nt*16 + (lane & 15);
    int k = kt*32 + ((lane >> 4) << 3) + j;
    W2f[i] = (k < CMID) ? f2bf(W2[n*CMID + k]) : (u16)0;
  }
}

// ============================================================ FPS v3
// Scalar distance update (bit-identical to passing v1: no fma, L->R adds).
// dist >= 0 -> float bits monotonic as u32. Unique u64 key = bits<<32 | ~idx
// (max key == max dist, tie -> lowest idx; exact numpy argmax semantics).
// Wave reduce: 6-stage u32 max butterfly on dist-bits only (half the shuffle
// traffic of (val,idx)), then ballot+ffs picks the LOWEST lane holding the
// max; lane->index ranges are monotonic, so lowest lane == lowest index.
#define FPS_T 512

static __device__ __forceinline__ u64 kmax(u64 a, u64 b) { return a > b ? a : b; }

__global__ __launch_bounds__(FPS_T) void fps_kernel(
    const float* __restrict__ xyz,
    int* __restrict__ fps_idx, float* __restrict__ center_out) {
  #pragma clang fp contract(off)
  int b = blockIdx.x, t = threadIdx.x;
  const float* p = xyz + (size_t)b * NP * 3;
  __shared__ __align__(16) float s_xyz[NP][4];   // 64 KB, 16B rows for b128 broadcast
  __shared__ u64 s_part[2][8];
  for (int i = t; i < NP; i += FPS_T) {
    s_xyz[i][0] = p[i*3+0]; s_xyz[i][1] = p[i*3+1];
    s_xyz[i][2] = p[i*3+2]; s_xyz[i][3] = 0.f;
  }
  __syncthreads();
  const int PPT = NP / FPS_T;             // 8 points/thread
  int base = t * PPT;
  float px[PPT], py[PPT], pz[PPT], dist[PPT];
  #pragma unroll
  for (int j = 0; j < PPT; ++j) {
    px[j] = s_xyz[base+j][0]; py[j] = s_xyz[base+j][1]; pz[j] = s_xyz[base+j][2];
    dist[j] = INFINITY;
  }
  int lane = t & 63, w = t >> 6;
  u32 far = 0;
  float cx = s_xyz[0][0], cy = s_xyz[0][1], cz = s_xyz[0][2];
  for (int it = 0; it < NC; ++it) {
    if (t == 0) {
      fps_idx[b*NC + it] = (int)far;
      center_out[(size_t)(b*NC + it)*3 + 0] = cx;
      center_out[(size_t)(b*NC + it)*3 + 1] = cy;
      center_out[(size_t)(b*NC + it)*3 + 2] = cz;
    }
    // ---- update dists (exact order: (dx*dx + dy*dy) + dz*dz, no fma) + unique keys
    u64 k[PPT];
    #pragma unroll
    for (int j = 0; j < PPT; ++j) {
      float dx = px[j] - cx, dy = py[j] - cy, dz = pz[j] - cz;
      float d = (dx*dx + dy*dy) + dz*dz;
      float nd = fminf(dist[j], d);
      dist[j] = nd;
      k[j] = ((u64)__builtin_bit_cast(u32, nd) << 32) | (u32)~(u32)(base + j);
    }
    // ---- local tree argmax (3 levels; keys unique, so winner well-defined)
    u64 a0 = kmax(k[0], k[1]), a1 = kmax(k[2], k[3]);
    u64 a2 = kmax(k[4], k[5]), a3 = kmax(k[6], k[7]);
    u64 cur = kmax(kmax(a0, a1), kmax(a2, a3));
    u32 mybits = (u32)(cur >> 32);
    int myidx  = (int)~(u32)cur;
    // ---- wave butterfly on dist-bits only (u32 max, 6 stages)
    u32 wb = mybits;
    wb = max(wb, (u32)__shfl_xor((int)wb, 1));
    wb = max(wb, (u32)__shfl_xor((int)wb, 2));
    wb = max(wb, (u32)__shfl_xor((int)wb, 4));
    wb = max(wb, (u32)__shfl_xor((int)wb, 8));
    wb = max(wb, (u32)__shfl_xor((int)wb, 16));
    wb = max(wb, (u32)__shfl_xor((int)wb, 32));
    // lowest lane holding the max -> lowest index (lane->idx ranges monotonic)
    u64 bal = __ballot(mybits == wb);
    int winner = __ffsll((long long)bal) - 1;
    int widx = __shfl(myidx, winner);
    int par = it & 1;
    if (lane == 0) s_part[par][w] = ((u64)wb << 32) | (u32)~(u32)widx;
    __syncthreads();
    // ---- combine 8 wave partials (broadcast reads, 3-level tree)
    u64 q0 = kmax(s_part[par][0], s_part[par][1]);
    u64 q1 = kmax(s_part[par][2], s_part[par][3]);
    u64 q2 = kmax(s_part[par][4], s_part[par][5]);
    u64 q3 = kmax(s_part[par][6], s_part[par][7]);
    u64 best = kmax(kmax(q0, q1), kmax(q2, q3));
    far = ~(u32)best;
    f32x4 c4 = *(const f32x4*)&s_xyz[far][0];   // aligned broadcast ds_read_b128
    cx = c4.x; cy = c4.y; cz = c4.z;
  }
}

// ============================================================ kNN (unchanged)
__global__ __launch_bounds__(256) void knn_kernel(
    const float* __restrict__ xyz, const float* __restrict__ sq,
    const int* __restrict__ fps_idx, int* __restrict__ grp) {
  #pragma clang fp contract(off)
  int L = blockIdx.x;
  int b = L & 7, ci = L >> 3;
  int t = threadIdx.x;
  const float* p   = xyz + (size_t)b * NP * 3;
  const float* sqb = sq + b * NP;
  __shared__ float s_d[NP];
  __shared__ float s_pval[2][4];
  __shared__ int   s_pidx[2][4];
  int center = fps_idx[b*NC + ci];
  float cx = p[center*3+0], cy = p[center*3+1], cz = p[center*3+2];
  float sqi = sqb[center];
  const int PPT = NP / 256;
  #pragma unroll
  for (int k = 0; k < PPT; ++k) {
    int j = t + k * 256;
    float dot = (cx*p[j*3+0] + cy*p[j*3+1]) + cz*p[j*3+2];
    s_d[j] = (sqi - 2.0f*dot) + sqb[j];
  }
  __syncthreads();
  int base = t * PPT;
  float lv = INFINITY; int li = 0x7fffffff;
  #pragma unroll
  for (int j = 0; j < PPT; ++j) {
    float v = s_d[base + j];
    bool bt = v < lv;
    lv = bt ? v : lv; li = bt ? (base + j) : li;
  }
  int lane = t & 63, wave = t >> 6;
  int myidx = 0;
  for (int it = 0; it < KN; ++it) {
    float bv = lv; int bi = li;
    #pragma unroll
    for (int off = 1; off < 64; off <<= 1) {
      float ov = __shfl_xor(bv, off);
      int   oi = __shfl_xor(bi, off);
      bool take = (ov < bv) || (ov == bv && oi < bi);
      bv = take ? ov : bv; bi = take ? oi : bi;
    }
    int par = it & 1;
    if (lane == 0) { s_pval[par][wave] = bv; s_pidx[par][wave] = bi; }
    __syncthreads();
    bv = s_pval[par][0]; bi = s_pidx[par][0];
    #pragma unroll
    for (int w = 1; w < 4; ++w) {
      float ov = s_pval[par][w]; int oi = s_pidx[par][w];
      bool take = (ov < bv) || (ov == bv && oi < bi);
      bv = take ? ov : bv; bi = take ? oi : bi;
    }
    if (t == it) myidx = bi;
    if ((bi >> 4) == t) {
      s_d[bi] = INFINITY;
      lv = INFINITY; li = 0x7fffffff;
      #pragma unroll
      for (int j = 0; j < PPT; ++j) {
        float v = s_d[base + j];
        bool bt = v < lv;
        lv = bt ? v : lv; li = bt ? (base + j) : li;
      }
    }
  }
  if (t < KN) grp[((size_t)(b*NC + ci))*KN + t] = myidx;
}

// ============================================================ fused MLP + maxpool (MFMA bf16, unchanged)
__global__ __launch_bounds__(256) void mlp_kernel(
    const float* __restrict__ xyz, const float* __restrict__ fea,
    const u16* __restrict__ W1f, const u16* __restrict__ W2f,
    const float* __restrict__ A1, const float* __restrict__ B1,
    const float* __restrict__ A2, const float* __restrict__ B2,
    const int* __restrict__ grp, const float* __restrict__ center_xyz,
    float* __restrict__ new_fea) {
  int L = blockIdx.x;
  int b = L & 7, pi = L >> 3;
  size_t gbase = (size_t)b * NC + pi * 2;
  int t = threadIdx.x;
  int lane = t & 63, w = t >> 6;

  __shared__ u16 sx[64][168];
  __shared__ u16 sy1[64][200];
  __shared__ int s_gidx[64];
  __shared__ float s_c[2][3];

  if (t < 64) s_gidx[t] = grp[(gbase + (t >> 5)) * KN + (t & 31)];
  if (t < 6)  s_c[t/3][t%3] = center_xyz[(gbase + t/3)*3 + (t%3)];
  __syncthreads();

  {
    int r = t >> 2, q0 = (t & 3) * 32;
    const float* src = fea + ((size_t)b*NP + s_gidx[r])*CIN + q0;
    #pragma unroll
    for (int j = 0; j < 32; j += 8) {
      float4 v0 = *(const float4*)(src + j);
      float4 v1 = *(const float4*)(src + j + 4);
      u16x8 pk;
      pk[0]=f2bf(v0.x); pk[1]=f2bf(v0.y); pk[2]=f2bf(v0.z); pk[3]=f2bf(v0.w);
      pk[4]=f2bf(v1.x); pk[5]=f2bf(v1.y); pk[6]=f2bf(v1.z); pk[7]=f2bf(v1.w);
      *(u16x8*)&sx[r][q0 + j] = pk;
    }
  }
  if (t < 64) {
    int c = t >> 5;
    const float* g = xyz + ((size_t)b*NP + s_gidx[t])*3;
    sx[t][128] = f2bf(g[0] - s_c[c][0]);
    sx[t][129] = f2bf(g[1] - s_c[c][1]);
    sx[t][130] = f2bf(g[2] - s_c[c][2]);
    #pragma unroll
    for (int j = 131; j < 160; ++j) sx[t][j] = 0;
  }
  __syncthreads();

  const f32x4 zero = {0.f, 0.f, 0.f, 0.f};

  // ---- layer 1
  {
    f32x4 acc[4][3];
    #pragma unroll
    for (int mt = 0; mt < 4; ++mt)
      #pragma unroll
      for (int nt = 0; nt < 3; ++nt) acc[mt][nt] = zero;
    #pragma unroll
    for (int kt = 0; kt < 5; ++kt) {
      s16x8 a[4];
      #pragma unroll
      for (int mt = 0; mt < 4; ++mt)
        a[mt] = *(const s16x8*)&sx[mt*16 + (lane & 15)][kt*32 + ((lane >> 4) << 3)];
      s16x8 bf[3];
      #pragma unroll
      for (int nt = 0; nt < 3; ++nt)
        bf[nt] = *(const s16x8*)&W1f[(((w*3 + nt)*5 + kt)*64 + lane) * 8];
      #pragma unroll
      for (int mt = 0; mt < 4; ++mt)
        #pragma unroll
        for (int nt = 0; nt < 3; ++nt)
          acc[mt][nt] = __builtin_amdgcn_mfma_f32_16x16x32_bf16(a[mt], bf[nt], acc[mt][nt], 0, 0, 0);
    }
    #pragma unroll
    for (int nt = 0; nt < 3; ++nt) {
      int c = w*48 + nt*16 + (lane & 15);
      float av = A1[c], bv = B1[c];
      #pragma unroll
      for (int mt = 0; mt < 4; ++mt) {
        #pragma unroll
        for (int r = 0; r < 4; ++r) {
          float v = fmaxf(fmaf(acc[mt][nt][r], av, bv), 0.f);
          sy1[mt*16 + ((lane >> 4) << 2) + r][c] = f2bf(v);
        }
      }
    }
  }
  __syncthreads();

  // ---- layer 2 + BN/ReLU + maxpool
  {
    f32x4 acc[4][4];
    #pragma unroll
    for (int mt = 0; mt < 4; ++mt)
      #pragma unroll
      for (int nt = 0; nt < 4; ++nt) acc[mt][nt] = zero;
    #pragma unroll
    for (int kt = 0; kt < 6; ++kt) {
      s16x8 a[4];
      #pragma unroll
      for (int mt = 0; mt < 4; ++mt)
        a[mt] = *(const s16x8*)&sy1[mt*16 + (lane & 15)][kt*32 + ((lane >> 4) << 3)];
      s16x8 bf[4];
      #pragma unroll
      for (int nt = 0; nt < 4; ++nt)
        bf[nt] = *(const s16x8*)&W2f[(((w*4 + nt)*6 + kt)*64 + lane) * 8];
      #pragma unroll
      for (int mt = 0; mt < 4; ++mt)
        #pragma unroll
        for (int nt = 0; nt < 4; ++nt)
          acc[mt][nt] = __builtin_amdgcn_mfma_f32_16x16x32_bf16(a[mt], bf[nt], acc[mt][nt], 0, 0, 0);
    }
    #pragma unroll
    for (int nt = 0; nt < 4; ++nt) {
      int c = w*64 + nt*16 + (lane & 15);
      float av = A2[c], bv = B2[c];
      float c0 = 0.f, c1 = 0.f;
      #pragma unroll
      for (int mt = 0; mt < 2; ++mt)
        #pragma unroll
        for (int r = 0; r < 4; ++r)
          c0 = fmaxf(c0, fmaf(acc[mt][nt][r], av, bv));
      #pragma unroll
      for (int mt = 2; mt < 4; ++mt)
        #pragma unroll
        for (int r = 0; r < 4; ++r)
          c1 = fmaxf(c1, fmaf(acc[mt][nt][r], av, bv));
      c0 = fmaxf(c0, __shfl_xor(c0, 16)); c0 = fmaxf(c0, __shfl_xor(c0, 32));
      c1 = fmaxf(c1, __shfl_xor(c1, 16)); c1 = fmaxf(c1, __shfl_xor(c1, 32));
      if (lane < 16)      new_fea[gbase*COUT + c] = c0;
      else if (lane < 32) new_fea[(gbase + 1)*COUT + c] = c1;
    }
  }
}

// ============================================================ launch
extern "C" void kernel_launch(void* const* d_in, const int* in_sizes, int n_in,
                              void* d_out, int out_size, void* d_ws, size_t ws_size,
                              hipStream_t stream) {
  const float* xyz = (const float*)d_in[0];
  const float* fea = (const float*)d_in[1];
  const float* W1  = (const float*)d_in[2];
  const float* b1  = (const float*)d_in[3];
  const float* g1  = (const float*)d_in[4];
  const float* be1 = (const float*)d_in[5];
  const float* m1  = (const float*)d_in[6];
  const float* v1  = (const float*)d_in[7];
  const float* W2  = (const float*)d_in[8];
  const float* b2  = (const float*)d_in[9];
  const float* g2  = (const float*)d_in[10];
  const float* be2 = (const float*)d_in[11];
  const float* m2  = (const float*)d_in[12];
  const float* v2  = (const float*)d_in[13];

  char* ws = (char*)d_ws;
  float* sq   = (float*)(ws + OFF_SQ);
  int*   fpsi = (int*)  (ws + OFF_FPS);
  int*   grp  = (int*)  (ws + OFF_GRP);
  float* A1   = (float*)(ws + OFF_A1);
  float* B1   = (float*)(ws + OFF_B1);
  float* A2   = (float*)(ws + OFF_A2);
  float* B2   = (float*)(ws + OFF_B2);
  u16*   W1f  = (u16*)  (ws + OFF_W1F);
  u16*   W2f  = (u16*)  (ws + OFF_W2F);

  float* out        = (float*)d_out;
  float* center_out = out;                   // [BS][NC][3]
  float* new_fea    = out + (size_t)BS*NC*3; // [BS][NC][COUT]

  prep_kernel<<<192, 256, 0, stream>>>(xyz, W1, W2, b1,g1,be1,m1,v1, b2,g2,be2,m2,v2,
                                       sq, A1,B1,A2,B2, W1f, W2f);
  fps_kernel<<<BS, FPS_T, 0, stream>>>(xyz, fpsi, center_out);
  knn_kernel<<<BS*NC, 256, 0, stream>>>(xyz, sq, fpsi, grp);
  mlp_kernel<<<BS*NC/2, 256, 0, stream>>>(xyz, fea, W1f, W2f, A1,B1,A2,B2,
                                          grp, center_out, new_fea);
}